// Round 1
// baseline (1115.118 us; speedup 1.0000x reference)
//
#include <hip/hip_runtime.h>

// Problem constants
constexpr int Bn  = 128;
constexpr int Tn  = 48000;
constexpr int NFn = 2999;   // fast frames
constexpr int NSn = 999;    // slow frames
constexpr int G3n = 192;    // 3*GH
constexpr int GHn = 64;

// ---------------------------------------------------------------------------
// Kernel 1: GI[b, t, j] = b_ih[j] + sum_{k<96} x[b, t*48+k] * W_ih[j, k]
// Block: 192 threads, handles one b and 32 consecutive t.
// W_ih staged transposed in LDS in two k-halves (48 each) to stay < 64KB.
// Each thread: 4 consecutive j (float4 W read) x 8 t (x broadcast) register tile.
// ---------------------------------------------------------------------------
__global__ __launch_bounds__(192) void gi_kernel(const float* __restrict__ x,
                                                 const float* __restrict__ W_ih,
                                                 const float* __restrict__ b_ih,
                                                 float* __restrict__ GI) {
  __shared__ __align__(16) float WT[48 * 196];   // [k][j] padded stride 196
  __shared__ float xs[1584];                     // 31*48+96 samples
  const int tile = blockIdx.x;        // 0..31
  const int b    = blockIdx.y;        // 0..127
  const int t0   = tile * 32;
  const int nt   = min(32, NSn - t0); // 32 or 7 (last tile)
  const int tid  = threadIdx.x;

  const int span = (nt - 1) * 48 + 96;
  for (int i = tid; i < 1584; i += 192)
    xs[i] = (i < span) ? x[(size_t)b * Tn + t0 * 48 + i] : 0.0f;

  const int jq = tid % 48;   // j-quad index
  const int tg = tid / 48;   // t-group (0..3)
  const int j0 = jq * 4;

  float acc[8][4];
#pragma unroll
  for (int u = 0; u < 8; ++u)
#pragma unroll
    for (int jj = 0; jj < 4; ++jj) acc[u][jj] = b_ih[j0 + jj];

  for (int half = 0; half < 2; ++half) {
    __syncthreads();
    for (int e = tid; e < 192 * 48; e += 192) {
      int j = e / 48, k = e % 48;
      WT[k * 196 + j] = W_ih[j * 96 + half * 48 + k];
    }
    __syncthreads();
    for (int k = 0; k < 48; ++k) {
      float4 w = *(const float4*)&WT[k * 196 + j0];
#pragma unroll
      for (int u = 0; u < 8; ++u) {
        float xv = xs[(tg * 8 + u) * 48 + half * 48 + k];
        acc[u][0] = fmaf(xv, w.x, acc[u][0]);
        acc[u][1] = fmaf(xv, w.y, acc[u][1]);
        acc[u][2] = fmaf(xv, w.z, acc[u][2]);
        acc[u][3] = fmaf(xv, w.w, acc[u][3]);
      }
    }
  }

#pragma unroll
  for (int u = 0; u < 8; ++u) {
    int tl = tg * 8 + u;
    if (tl < nt) {
      float4 st = make_float4(acc[u][0], acc[u][1], acc[u][2], acc[u][3]);
      *(float4*)&GI[(size_t)(b * NSn + t0 + tl) * G3n + j0] = st;
    }
  }
}

// ---------------------------------------------------------------------------
// Kernel 2: sequential GRU over 999 steps. One block per batch element.
// 192 threads: thread j computes gate pre-activation j (W_hh row in VGPRs,
// h broadcast from LDS via float4). Threads 0..63 do the gating + h update.
// GI streamed with 2-step prefetch to cover HBM latency.
// ---------------------------------------------------------------------------
__device__ __forceinline__ float fsigmoid(float v) {
  return __fdividef(1.0f, 1.0f + __expf(-v));
}
__device__ __forceinline__ float ftanh_f(float v) {
  return 1.0f - __fdividef(2.0f, __expf(2.0f * v) + 1.0f);
}

__global__ __launch_bounds__(192) void gru_kernel(const float* __restrict__ GI,
                                                  const float* __restrict__ W_hh,
                                                  const float* __restrict__ b_hh,
                                                  float* __restrict__ hs) {
  __shared__ __align__(16) float hbuf[64];
  __shared__ float gates[192];
  __shared__ float gin[64];
  const int b = blockIdx.x;
  const int j = threadIdx.x;

  float4 wr[16];
#pragma unroll
  for (int q = 0; q < 16; ++q) wr[q] = *(const float4*)&W_hh[j * 64 + q * 4];
  const float bhh = b_hh[j];

  if (j < 64) hbuf[j] = 0.0f;
  __syncthreads();

  const float* gp  = GI + (size_t)b * NSn * G3n + j;
  float* hsp       = hs + (size_t)b * NSn * GHn;
  float g0 = gp[0];
  float g1 = gp[G3n];

  for (int t = 0; t < NSn; ++t) {
    float g2 = gp[(size_t)min(t + 2, NSn - 1) * G3n];  // prefetch
    float acc = bhh;
    const float4* h4 = (const float4*)hbuf;
#pragma unroll
    for (int q = 0; q < 16; ++q) {
      float4 hq = h4[q];
      acc = fmaf(hq.x, wr[q].x, acc);
      acc = fmaf(hq.y, wr[q].y, acc);
      acc = fmaf(hq.z, wr[q].z, acc);
      acc = fmaf(hq.w, wr[q].w, acc);
    }
    if (j < 128) {
      gates[j] = g0 + acc;          // r,z parts: i + h (b_hh folded into acc)
    } else {
      gates[j] = acc;               // n part: h-only (dot + b_hh_n)
      gin[j - 128] = g0;            // i_n
    }
    __syncthreads();
    if (j < 64) {
      float hold = hbuf[j];
      float r = fsigmoid(gates[j]);
      float z = fsigmoid(gates[j + 64]);
      float n = ftanh_f(fmaf(r, gates[j + 128], gin[j]));
      float hn = fmaf(z, hold - n, n);     // (1-z)*n + z*h
      hbuf[j] = hn;
      hsp[t * GHn + j] = hn;
    }
    __syncthreads();
    g0 = g1; g1 = g2;
  }
}

// ---------------------------------------------------------------------------
// Kernel 3: fast path + overlap-add. Block handles one b and frames
// [f0, f0+32] (33 frames incl. halo); owns output samples
// [f0*16+16, f0*16+528) (block 0 also owns [0,16)). Each sample written once.
// ---------------------------------------------------------------------------
__global__ __launch_bounds__(256) void out_kernel(const float* __restrict__ x,
                                                  const float* __restrict__ hs,
                                                  const float* __restrict__ W_cs,
                                                  const float* __restrict__ b_cs,
                                                  const float* __restrict__ W1,
                                                  const float* __restrict__ b1,
                                                  const float* __restrict__ W2,
                                                  const float* __restrict__ b2,
                                                  float* __restrict__ out) {
  __shared__ float xsl[544];
  __shared__ float W1T[64 * 65];   // [k][o] padded
  __shared__ float W2T[64 * 33];   // [k][o] padded
  __shared__ float WcT[64 * 33];   // [k][i] padded
  __shared__ float cloc[33 * 32];
  __shared__ float h1loc[33 * 64];
  __shared__ float yloc[33 * 32];
  __shared__ float hrows[12 * 64];
  __shared__ float bb1[64], bb2[32], bcs[32];

  const int fb  = blockIdx.x;
  const int b   = blockIdx.y;
  const int f0  = fb * 32;
  const int nf  = min(33, NFn - f0);
  const int tid = threadIdx.x;

  for (int i = tid; i < 544; i += 256) {
    int g = f0 * 16 + i;
    xsl[i] = (g < Tn) ? x[(size_t)b * Tn + g] : 0.0f;
  }
  for (int e = tid; e < 64 * 64; e += 256) {
    int o = e >> 6, k = e & 63;
    W1T[k * 65 + o] = W1[e];
  }
  for (int e = tid; e < 32 * 64; e += 256) {
    int o = e >> 6, k = e & 63;
    W2T[k * 33 + o] = W2[e];
    WcT[k * 33 + o] = W_cs[e];
  }
  const int ts_base = max(f0 / 3 - 1, 0);
  const int ts_max  = max((f0 + nf - 1) / 3 - 1, 0);
  const int cnt     = ts_max - ts_base + 1;   // <= 12
  for (int i = tid; i < cnt * 64; i += 256) {
    int ts = ts_base + (i >> 6);
    hrows[i] = hs[((size_t)b * NSn + ts) * GHn + (i & 63)];
  }
  if (tid < 64) bb1[tid] = b1[tid];
  if (tid < 32) { bb2[tid] = b2[tid]; bcs[tid] = b_cs[tid]; }
  __syncthreads();

  // conditioning vector per frame
  for (int o = tid; o < nf * 32; o += 256) {
    int lf = o >> 5, i = o & 31;
    int ts = max((f0 + lf) / 3 - 1, 0);
    const float* hr = &hrows[(ts - ts_base) * 64];
    float acc = bcs[i];
#pragma unroll
    for (int k = 0; k < 64; ++k) acc = fmaf(WcT[k * 33 + i], hr[k], acc);
    cloc[o] = acc;
  }
  __syncthreads();

  // h1 = relu(W1 @ [fast; c] + b1)
  for (int o = tid; o < nf * 64; o += 256) {
    int lf = o >> 6, oo = o & 63;
    float acc = bb1[oo];
    const float* xf = &xsl[lf * 16];
    const float* cf = &cloc[lf * 32];
#pragma unroll
    for (int k = 0; k < 32; ++k) acc = fmaf(W1T[k * 65 + oo], xf[k], acc);
#pragma unroll
    for (int k = 0; k < 32; ++k) acc = fmaf(W1T[(k + 32) * 65 + oo], cf[k], acc);
    h1loc[o] = fmaxf(acc, 0.0f);
  }
  __syncthreads();

  // y = W2 @ h1 + b2
  for (int o = tid; o < nf * 32; o += 256) {
    int lf = o >> 5, oo = o & 31;
    const float* hf = &h1loc[lf * 64];
    float acc = bb2[oo];
#pragma unroll
    for (int k = 0; k < 64; ++k) acc = fmaf(W2T[k * 33 + oo], hf[k], acc);
    yloc[o] = acc;
  }
  __syncthreads();

  // overlap-add: sample s gets y[f1][s%16] (if f1 valid) + y[f1-1][s%16+16]
  const int s0 = f0 * 16 + 16;
  const int s1 = min(s0 + 512, Tn);
  for (int s = s0 + tid; s < s1; s += 256) {
    int f1  = s >> 4;
    int o1  = s & 15;
    int lf1 = f1 - f0;                       // in [1, 32]
    float v = yloc[(lf1 - 1) * 32 + o1 + 16];
    if (lf1 < nf) v += yloc[lf1 * 32 + o1];
    out[(size_t)b * Tn + s] = v;
  }
  if (fb == 0 && tid < 16) out[(size_t)b * Tn + tid] = yloc[tid];
}

// ---------------------------------------------------------------------------
extern "C" void kernel_launch(void* const* d_in, const int* in_sizes, int n_in,
                              void* d_out, int out_size, void* d_ws, size_t ws_size,
                              hipStream_t stream) {
  const float* x    = (const float*)d_in[0];
  const float* W_ih = (const float*)d_in[1];
  const float* W_hh = (const float*)d_in[2];
  const float* b_ih = (const float*)d_in[3];
  const float* b_hh = (const float*)d_in[4];
  const float* W_cs = (const float*)d_in[5];
  const float* b_cs = (const float*)d_in[6];
  const float* W1   = (const float*)d_in[7];
  const float* b1   = (const float*)d_in[8];
  const float* W2   = (const float*)d_in[9];
  const float* b2   = (const float*)d_in[10];
  float* out = (float*)d_out;

  float* GI = (float*)d_ws;                        // 128*999*192 fp32 = 98.2MB
  float* hs = GI + (size_t)Bn * NSn * G3n;         // 128*999*64  fp32 = 32.7MB

  gi_kernel<<<dim3(32, Bn), 192, 0, stream>>>(x, W_ih, b_ih, GI);
  gru_kernel<<<Bn, 192, 0, stream>>>(GI, W_hh, b_hh, hs);
  out_kernel<<<dim3(94, Bn), 256, 0, stream>>>(x, hs, W_cs, b_cs, W1, b1, W2, b2, out);
}